// Round 11
// baseline (678.337 us; speedup 1.0000x reference)
//
#include <hip/hip_runtime.h>
#include <hip/hip_cooperative_groups.h>

namespace cg = cooperative_groups;

#define N_VOX 100000
#define K_OFF 27
#define M_PAIR 60000
#define NPAIR (K_OFF * M_PAIR)
#define TILES_PER_K (M_PAIR / 16)         // 3750
#define TILES_TOTAL (K_OFF * TILES_PER_K) // 101250
#define CIN 64
#define COUT 64
#define BN_EPS 1e-5f

typedef __attribute__((ext_vector_type(8))) short bf16x8;
typedef __attribute__((ext_vector_type(8))) unsigned short u16x8;
typedef __attribute__((ext_vector_type(4))) float f32x4;

__device__ __forceinline__ unsigned short f32_to_bf16(float f) {
    unsigned int u = __float_as_uint(f);
    u += 0x7FFFu + ((u >> 16) & 1u);
    return (unsigned short)(u >> 16);
}
__device__ __forceinline__ float bf16_to_f32(unsigned short b) {
    return __uint_as_float(((unsigned int)b) << 16);
}

// ---------------- cooperative mega-kernel (grid-size-agnostic) ----------------
__global__ __launch_bounds__(256, 4) void mega_kernel(
    const float* __restrict__ feats, const float* __restrict__ W,
    const float* __restrict__ gamma, const float* __restrict__ beta,
    const float* __restrict__ rmean, const float* __restrict__ rvar,
    const int* __restrict__ in_idx, const int* __restrict__ out_idx,
    float* __restrict__ out,
    int* __restrict__ cnt, int* __restrict__ total, int* __restrict__ seg,
    int* __restrict__ rank, unsigned short* __restrict__ fb,
    unsigned short* __restrict__ Wt, unsigned short* __restrict__ contrib)
{
    cg::grid_group grid = cg::this_grid();
    __shared__ alignas(16) unsigned short s_lds[4][16 * 72];
    __shared__ int s_part[256];
    __shared__ int s_bbase;

    const int nblk = gridDim.x;
    const int tid = blockIdx.x * 256 + threadIdx.x;
    const int nthr = nblk * 256;
    const int lane = threadIdx.x & 63;
    const int wid = threadIdx.x >> 6;
    const int wave_gid = blockIdx.x * 4 + wid;
    const int nwaves = nblk * 4;

    // ---- phase 0: zero counters + convert feats/W ----
    for (int i = tid; i < N_VOX; i += nthr) cnt[i] = 0;
    if (tid == 0) *total = 0;
    for (int e = tid; e < (N_VOX * CIN) / 4; e += nthr) {
        const int e4 = e * 4;
        const float4 v = *(const float4*)(feats + e4);
        ushort4 b;
        b.x = f32_to_bf16(v.x);
        b.y = f32_to_bf16(v.y);
        b.z = f32_to_bf16(v.z);
        b.w = f32_to_bf16(v.w);
        *(ushort4*)(fb + e4) = b;
    }
    for (int e = tid; e < K_OFF * CIN * COUT; e += nthr) {
        const int k = e / (CIN * COUT);
        const int r = e % (CIN * COUT);
        Wt[k * CIN * COUT + (r % COUT) * CIN + (r / COUT)] = f32_to_bf16(W[e]);
    }
    grid.sync();

    // ---- phase 1: hist + rank (atomic return value IS the rank) ----
    for (int e = tid; e < NPAIR; e += nthr)
        rank[e] = atomicAdd(&cnt[out_idx[e]], 1);
    grid.sync();

    // ---- phase 2: segment alloc (LDS scan per 256 voxels, grid-strided) ----
    {
        const int t = threadIdx.x;
        for (int vb = blockIdx.x * 256; vb < N_VOX; vb += nblk * 256) {
            const int v = vb + t;
            const int c = (v < N_VOX) ? cnt[v] : 0;
            s_part[t] = c;
            __syncthreads();
            for (int o = 1; o < 256; o <<= 1) {
                int x = (t >= o) ? s_part[t - o] : 0;
                __syncthreads();
                s_part[t] += x;
                __syncthreads();
            }
            if (t == 255) s_bbase = atomicAdd(total, s_part[255]);
            __syncthreads();
            if (v < N_VOX) seg[v] = s_bbase + (s_part[t] - c);
            __syncthreads();   // protect s_part/s_bbase before next iteration
        }
    }
    grid.sync();

    // ---- phase 3: gather-GEMM + sorted-slot full-line stores (no atomics) ----
    {
        const int col = lane & 15;
        const int quad = lane >> 4;
        unsigned short* L = s_lds[wid];
        const int chunk = (TILES_TOTAL + nwaves - 1) / nwaves;
        const int start = wave_gid * chunk;
        const int end = (start + chunk < TILES_TOTAL) ? start + chunk : TILES_TOTAL;
        int kcur = -1;
        bf16x8 Bf[4][2];
        for (int idx = start; idx < end; ++idx) {
            const int k = idx / TILES_PER_K;
            if (k != kcur) {                 // <=2 reloads per wave (L2-hit)
                kcur = k;
                const short* Wk = (const short*)(Wt + k * CIN * COUT);
#pragma unroll
                for (int t = 0; t < 4; ++t) {
                    const short* p = Wk + (t * 16 + col) * CIN + quad * 8;
                    Bf[t][0] = *(const bf16x8*)(p);
                    Bf[t][1] = *(const bf16x8*)(p + 32);
                }
            }
            const int m0 = k * M_PAIR + (idx - k * TILES_PER_K) * 16;

            int slot = 0;
            if (lane < 16)
                slot = seg[out_idx[m0 + lane]] + rank[m0 + lane];

            const int rin = in_idx[m0 + col];
            const short* fp = (const short*)fb + (size_t)rin * CIN + quad * 8;
            const bf16x8 A0 = *(const bf16x8*)(fp);
            const bf16x8 A1 = *(const bf16x8*)(fp + 32);

            f32x4 acc[4];
#pragma unroll
            for (int t = 0; t < 4; ++t) {
                f32x4 z = {0.f, 0.f, 0.f, 0.f};
                acc[t] = __builtin_amdgcn_mfma_f32_16x16x32_bf16(A0, Bf[t][0], z, 0, 0, 0);
                acc[t] = __builtin_amdgcn_mfma_f32_16x16x32_bf16(A1, Bf[t][1], acc[t], 0, 0, 0);
            }
#pragma unroll
            for (int r = 0; r < 4; ++r) {
                const int row = quad * 4 + r;
#pragma unroll
                for (int t = 0; t < 4; ++t)
                    L[row * 72 + t * 16 + col] = f32_to_bf16(acc[t][r]);
            }
#pragma unroll
            for (int itr = 0; itr < 2; ++itr) {
                const int row = itr * 8 + (lane >> 3);
                const int chnk = lane & 7;
                const int pos = __shfl(slot, row, 64);
                const u16x8 v = *(const u16x8*)(L + row * 72 + chnk * 8);
                *(u16x8*)(contrib + (size_t)pos * 64 + chnk * 8) = v;
            }
        }
    }
    grid.sync();

    // ---- phase 4: streaming segmented sum + BN + ReLU ----
    {
        const int half = lane >> 5;
        const int l = lane & 31;
        for (int v = wave_gid; v < N_VOX; v += nwaves) {
            const int s = seg[v];
            const int n = cnt[v];
            const unsigned int* p = (const unsigned int*)(contrib + (size_t)s * 64) + l;
            float c0 = 0.f, c1 = 0.f, d0 = 0.f, d1 = 0.f;
            int j = half;
            for (; j + 2 < n; j += 4) {
                const unsigned int u0 = p[(size_t)j * 32];
                const unsigned int u1 = p[(size_t)(j + 2) * 32];
                c0 += bf16_to_f32((unsigned short)u0);
                c1 += bf16_to_f32((unsigned short)(u0 >> 16));
                d0 += bf16_to_f32((unsigned short)u1);
                d1 += bf16_to_f32((unsigned short)(u1 >> 16));
            }
            if (j < n) {
                const unsigned int u0 = p[(size_t)j * 32];
                c0 += bf16_to_f32((unsigned short)u0);
                c1 += bf16_to_f32((unsigned short)(u0 >> 16));
            }
            c0 += d0;
            c1 += d1;
            c0 += __shfl_xor(c0, 32, 64);
            c1 += __shfl_xor(c1, 32, 64);
            if (half == 0) {
                const int ch = 2 * l;
                const float inv0 = rsqrtf(rvar[ch] + BN_EPS);
                const float inv1 = rsqrtf(rvar[ch + 1] + BN_EPS);
                const float y0 = (c0 - rmean[ch]) * (inv0 * gamma[ch]) + beta[ch];
                const float y1 = (c1 - rmean[ch + 1]) * (inv1 * gamma[ch + 1]) + beta[ch + 1];
                float2 r;
                r.x = fmaxf(y0, 0.f);
                r.y = fmaxf(y1, 0.f);
                *(float2*)(out + (size_t)v * 64 + ch) = r;
            }
        }
    }
}

// ---------- round-9 path (fallback if cooperative launch unavailable) ----------
__global__ __launch_bounds__(256) void prep_rank_kernel(
    const int* __restrict__ oix, int* __restrict__ cnt, int* __restrict__ rank,
    const float* __restrict__ feats, unsigned short* __restrict__ fb,
    const float* __restrict__ W, unsigned short* __restrict__ Wt)
{
    const int e = blockIdx.x * blockDim.x + threadIdx.x;
    if (e < NPAIR) rank[e] = atomicAdd(&cnt[oix[e]], 1);
    if (e < (N_VOX * CIN) / 4) {
        const int e4 = e * 4;
        const float4 v = *(const float4*)(feats + e4);
        ushort4 b;
        b.x = f32_to_bf16(v.x);
        b.y = f32_to_bf16(v.y);
        b.z = f32_to_bf16(v.z);
        b.w = f32_to_bf16(v.w);
        *(ushort4*)(fb + e4) = b;
    }
    if (e < K_OFF * CIN * COUT) {
        const int k = e / (CIN * COUT);
        const int r = e % (CIN * COUT);
        Wt[k * CIN * COUT + (r % COUT) * CIN + (r / COUT)] = f32_to_bf16(W[e]);
    }
}

__global__ __launch_bounds__(256) void alloc_kernel(
    const int* __restrict__ cnt, int* __restrict__ total, int* __restrict__ seg)
{
    __shared__ int part[256];
    __shared__ int bbase;
    const int t = threadIdx.x;
    const int v = blockIdx.x * 256 + t;
    const int c = (v < N_VOX) ? cnt[v] : 0;
    part[t] = c;
    __syncthreads();
    for (int o = 1; o < 256; o <<= 1) {
        int x = (t >= o) ? part[t - o] : 0;
        __syncthreads();
        part[t] += x;
        __syncthreads();
    }
    if (t == 255) bbase = atomicAdd(total, part[255]);
    __syncthreads();
    if (v < N_VOX) seg[v] = bbase + (part[t] - c);
}

__global__ __launch_bounds__(256) void conv_scatter_kernel(
    const unsigned short* __restrict__ fb, const unsigned short* __restrict__ Wt,
    const int* __restrict__ in_idx, const int* __restrict__ out_idx,
    const int* __restrict__ rank, const int* __restrict__ seg,
    unsigned short* __restrict__ contrib)
{
    __shared__ alignas(16) unsigned short lds[4][16 * 72];
    const int k = blockIdx.y;
    const int lane = threadIdx.x & 63;
    const int wid = threadIdx.x >> 6;
    const int w = blockIdx.x * 4 + wid;
    if (w >= 125) return;
    const int col = lane & 15;
    const int quad = lane >> 4;
    unsigned short* L = lds[wid];

    bf16x8 Bf[4][2];
    const short* Wk = (const short*)(Wt + k * CIN * COUT);
#pragma unroll
    for (int t = 0; t < 4; ++t) {
        const short* p = Wk + (t * 16 + col) * CIN + quad * 8;
        Bf[t][0] = *(const bf16x8*)(p);
        Bf[t][1] = *(const bf16x8*)(p + 32);
    }
    const int base = k * M_PAIR;
    for (int it = 0; it < 30; ++it) {
        const int m0 = base + (w * 30 + it) * 16;
        int slot = 0;
        if (lane < 16)
            slot = seg[out_idx[m0 + lane]] + rank[m0 + lane];
        const int rin = in_idx[m0 + col];
        const short* fp = (const short*)fb + (size_t)rin * CIN + quad * 8;
        const bf16x8 A0 = *(const bf16x8*)(fp);
        const bf16x8 A1 = *(const bf16x8*)(fp + 32);
        f32x4 acc[4];
#pragma unroll
        for (int t = 0; t < 4; ++t) {
            f32x4 z = {0.f, 0.f, 0.f, 0.f};
            acc[t] = __builtin_amdgcn_mfma_f32_16x16x32_bf16(A0, Bf[t][0], z, 0, 0, 0);
            acc[t] = __builtin_amdgcn_mfma_f32_16x16x32_bf16(A1, Bf[t][1], acc[t], 0, 0, 0);
        }
#pragma unroll
        for (int r = 0; r < 4; ++r) {
            const int row = quad * 4 + r;
#pragma unroll
            for (int t = 0; t < 4; ++t)
                L[row * 72 + t * 16 + col] = f32_to_bf16(acc[t][r]);
        }
#pragma unroll
        for (int itr = 0; itr < 2; ++itr) {
            const int row = itr * 8 + (lane >> 3);
            const int chunk = lane & 7;
            const int pos = __shfl(slot, row, 64);
            const u16x8 v = *(const u16x8*)(L + row * 72 + chunk * 8);
            *(u16x8*)(contrib + (size_t)pos * 64 + chunk * 8) = v;
        }
    }
}

__global__ __launch_bounds__(256) void gather_bn_kernel(
    const unsigned short* __restrict__ contrib, const int* __restrict__ seg,
    const int* __restrict__ cnt,
    const float* __restrict__ gamma, const float* __restrict__ beta,
    const float* __restrict__ mean, const float* __restrict__ var,
    float* __restrict__ out)
{
    const int v = blockIdx.x * 4 + (threadIdx.x >> 6);
    if (v >= N_VOX) return;
    const int lane = threadIdx.x & 63;
    const int half = lane >> 5;
    const int l = lane & 31;
    const int s = seg[v];
    const int n = cnt[v];
    const unsigned int* p = (const unsigned int*)(contrib + (size_t)s * 64) + l;
    float c0 = 0.f, c1 = 0.f, d0 = 0.f, d1 = 0.f;
    int j = half;
    for (; j + 2 < n; j += 4) {
        const unsigned int u0 = p[(size_t)j * 32];
        const unsigned int u1 = p[(size_t)(j + 2) * 32];
        c0 += bf16_to_f32((unsigned short)u0);
        c1 += bf16_to_f32((unsigned short)(u0 >> 16));
        d0 += bf16_to_f32((unsigned short)u1);
        d1 += bf16_to_f32((unsigned short)(u1 >> 16));
    }
    if (j < n) {
        const unsigned int u0 = p[(size_t)j * 32];
        c0 += bf16_to_f32((unsigned short)u0);
        c1 += bf16_to_f32((unsigned short)(u0 >> 16));
    }
    c0 += d0;
    c1 += d1;
    c0 += __shfl_xor(c0, 32, 64);
    c1 += __shfl_xor(c1, 32, 64);
    if (half == 0) {
        const int ch = 2 * l;
        const float inv0 = rsqrtf(var[ch] + BN_EPS);
        const float inv1 = rsqrtf(var[ch + 1] + BN_EPS);
        const float y0 = (c0 - mean[ch]) * (inv0 * gamma[ch]) + beta[ch];
        const float y1 = (c1 - mean[ch + 1]) * (inv1 * gamma[ch + 1]) + beta[ch + 1];
        float2 r;
        r.x = fmaxf(y0, 0.f);
        r.y = fmaxf(y1, 0.f);
        *(float2*)(out + (size_t)v * 64 + ch) = r;
    }
}

// ---------- tiny fallback if ws too small ----------
__global__ __launch_bounds__(256) void prep_small_kernel(
    const float* __restrict__ feats, unsigned short* __restrict__ fb,
    float* __restrict__ out, const float* __restrict__ W,
    unsigned short* __restrict__ Wt)
{
    const int e = blockIdx.x * blockDim.x + threadIdx.x;
    if (e < (N_VOX * CIN) / 4) {
        const int e4 = e * 4;
        const float4 v = *(const float4*)(feats + e4);
        ushort4 b;
        b.x = f32_to_bf16(v.x);
        b.y = f32_to_bf16(v.y);
        b.z = f32_to_bf16(v.z);
        b.w = f32_to_bf16(v.w);
        *(ushort4*)(fb + e4) = b;
        *(float4*)(out + e4) = make_float4(0.f, 0.f, 0.f, 0.f);
    }
    if (e < K_OFF * CIN * COUT) {
        const int k = e / (CIN * COUT);
        const int r = e % (CIN * COUT);
        Wt[k * CIN * COUT + (r % COUT) * CIN + (r / COUT)] = f32_to_bf16(W[e]);
    }
}

__global__ __launch_bounds__(256) void conv_atomic_kernel(
    const unsigned short* __restrict__ fb, const unsigned short* __restrict__ Wt,
    const int* __restrict__ in_idx, const int* __restrict__ out_idx,
    float* __restrict__ out)
{
    const int k = blockIdx.y;
    const int lane = threadIdx.x & 63;
    const int wave = blockIdx.x * 4 + (threadIdx.x >> 6);
    const int col = lane & 15;
    const int quad = lane >> 4;
    bf16x8 Bf[4][2];
    const short* Wk = (const short*)(Wt + k * CIN * COUT);
#pragma unroll
    for (int t = 0; t < 4; ++t) {
        const short* p = Wk + (t * 16 + col) * CIN + quad * 8;
        Bf[t][0] = *(const bf16x8*)(p);
        Bf[t][1] = *(const bf16x8*)(p + 32);
    }
    const int base = k * M_PAIR;
    for (int tile = wave; tile < M_PAIR / 16; tile += 128) {
        const int m0 = base + tile * 16;
        const int rin = in_idx[m0 + col];
        const short* fp = (const short*)fb + (size_t)rin * CIN + quad * 8;
        const bf16x8 A0 = *(const bf16x8*)(fp);
        const bf16x8 A1 = *(const bf16x8*)(fp + 32);
        f32x4 acc[4];
#pragma unroll
        for (int t = 0; t < 4; ++t) {
            f32x4 z = {0.f, 0.f, 0.f, 0.f};
            acc[t] = __builtin_amdgcn_mfma_f32_16x16x32_bf16(A0, Bf[t][0], z, 0, 0, 0);
            acc[t] = __builtin_amdgcn_mfma_f32_16x16x32_bf16(A1, Bf[t][1], acc[t], 0, 0, 0);
        }
        int vo[4];
#pragma unroll
        for (int r = 0; r < 4; ++r) vo[r] = out_idx[m0 + quad * 4 + r];
#pragma unroll
        for (int r = 0; r < 4; ++r) {
            float* op = out + (size_t)vo[r] * COUT + col;
#pragma unroll
            for (int t = 0; t < 4; ++t) atomicAdd(op + t * 16, acc[t][r]);
        }
    }
}

__global__ __launch_bounds__(256) void bn_relu_kernel(
    float* __restrict__ out,
    const float* __restrict__ gamma, const float* __restrict__ beta,
    const float* __restrict__ mean, const float* __restrict__ var)
{
    const int e = blockIdx.x * blockDim.x + threadIdx.x;
    if (e >= N_VOX * COUT) return;
    const int c = e & (COUT - 1);
    const float inv = rsqrtf(var[c] + BN_EPS);
    const float y = (out[e] - mean[c]) * (inv * gamma[c]) + beta[c];
    out[e] = fmaxf(y, 0.f);
}

// ---------- host ----------
extern "C" void kernel_launch(void* const* d_in, const int* in_sizes, int n_in,
                              void* d_out, int out_size, void* d_ws, size_t ws_size,
                              hipStream_t stream) {
    const float* feats = (const float*)d_in[0];
    const float* W     = (const float*)d_in[1];
    const float* gamma = (const float*)d_in[2];
    const float* beta  = (const float*)d_in[3];
    const float* rmean = (const float*)d_in[4];
    const float* rvar  = (const float*)d_in[5];
    const int* in_idx  = (const int*)d_in[6];
    const int* out_idx = (const int*)d_in[7];
    float* out = (float*)d_out;

    char* ws = (char*)d_ws;
    size_t off = 0;
    auto alloc = [&](size_t bytes) {
        size_t p = off;
        off = (off + bytes + 255) & ~(size_t)255;
        return p;
    };
    const size_t o_fb   = alloc((size_t)N_VOX * CIN * 2);
    const size_t o_wt   = alloc((size_t)K_OFF * CIN * COUT * 2);
    const size_t o_cnt  = alloc((size_t)N_VOX * 4);
    const size_t o_tot  = alloc(4);
    const size_t o_seg  = alloc((size_t)N_VOX * 4);
    const size_t o_rank = alloc((size_t)NPAIR * 4);
    const size_t o_ctr  = alloc((size_t)NPAIR * COUT * 2);
    const bool big = (ws_size >= off);

    unsigned short* fb  = (unsigned short*)(ws + o_fb);
    unsigned short* Wt  = (unsigned short*)(ws + o_wt);
    int* cnt            = (int*)(ws + o_cnt);
    int* total          = (int*)(ws + o_tot);
    int* seg            = (int*)(ws + o_seg);
    int* rank           = (int*)(ws + o_rank);
    unsigned short* ctr = (unsigned short*)(ws + o_ctr);

    if (!big) {
        const int ptot = (N_VOX * CIN) / 4;
        prep_small_kernel<<<(ptot + 255) / 256, 256, 0, stream>>>(feats, fb, out, W, Wt);
        conv_atomic_kernel<<<dim3(32, K_OFF), 256, 0, stream>>>(fb, Wt, in_idx, out_idx, out);
        const int total_e = N_VOX * COUT;
        bn_relu_kernel<<<(total_e + 255) / 256, 256, 0, stream>>>(out, gamma, beta, rmean, rvar);
        return;
    }

    // ---- size the cooperative grid from the REAL occupancy (host queries:
    // capture-safe, no stream ops) and verify the launch succeeded ----
    bool coop_ok = false;
    int blocksPerCU = 0;
    if (hipOccupancyMaxActiveBlocksPerMultiprocessor(&blocksPerCU,
            (const void*)mega_kernel, 256, 0) == hipSuccess && blocksPerCU > 0) {
        int dev = 0;
        hipGetDevice(&dev);
        int nCU = 0;
        hipDeviceGetAttribute(&nCU, hipDeviceAttributeMultiprocessorCount, dev);
        int grid = blocksPerCU * nCU;
        if (grid > 1024) grid = 1024;
        if (grid >= 64) {
            void* args[] = {
                (void*)&feats, (void*)&W, (void*)&gamma, (void*)&beta,
                (void*)&rmean, (void*)&rvar, (void*)&in_idx, (void*)&out_idx,
                (void*)&out, (void*)&cnt, (void*)&total, (void*)&seg,
                (void*)&rank, (void*)&fb, (void*)&Wt, (void*)&ctr,
            };
            coop_ok = (hipLaunchCooperativeKernel((void*)mega_kernel, dim3(grid),
                                                  dim3(256), args, 0, stream) == hipSuccess);
        }
    }

    if (!coop_ok) {
        // round-9 proven path (294 us) — deterministic fallback, graph-safe
        hipMemsetAsync(cnt, 0, (size_t)N_VOX * 4, stream);
        hipMemsetAsync(total, 0, 4, stream);
        prep_rank_kernel<<<(NPAIR + 255) / 256, 256, 0, stream>>>(
            out_idx, cnt, rank, feats, fb, W, Wt);
        alloc_kernel<<<(N_VOX + 255) / 256, 256, 0, stream>>>(cnt, total, seg);
        conv_scatter_kernel<<<dim3(32, K_OFF), 256, 0, stream>>>(
            fb, Wt, in_idx, out_idx, rank, seg, ctr);
        gather_bn_kernel<<<(N_VOX + 3) / 4, 256, 0, stream>>>(ctr, seg, cnt,
                                                              gamma, beta, rmean, rvar, out);
    }
}

// Round 12
// 303.555 us; speedup vs baseline: 2.2346x; 2.2346x over previous
//
#include <hip/hip_runtime.h>

#define N_VOX 100000
#define K_OFF 27
#define M_PAIR 60000
#define NPAIR (K_OFF * M_PAIR)
#define CIN 64
#define COUT 64
#define BN_EPS 1e-5f

typedef __attribute__((ext_vector_type(8))) short bf16x8;
typedef __attribute__((ext_vector_type(8))) unsigned short u16x8;
typedef __attribute__((ext_vector_type(4))) float f32x4;

__device__ __forceinline__ unsigned short f32_to_bf16(float f) {
    unsigned int u = __float_as_uint(f);
    u += 0x7FFFu + ((u >> 16) & 1u);
    return (unsigned short)(u >> 16);
}
__device__ __forceinline__ float bf16_to_f32(unsigned short b) {
    return __uint_as_float(((unsigned int)b) << 16);
}

// ---------- fused prep: hist atomic (rank = return value) + feats->bf16 + W^T ----------
__global__ __launch_bounds__(256) void prep_rank_kernel(
    const int* __restrict__ oix, int* __restrict__ cnt, int* __restrict__ rank,
    const float* __restrict__ feats, unsigned short* __restrict__ fb,
    const float* __restrict__ W, unsigned short* __restrict__ Wt)
{
    const int e = blockIdx.x * blockDim.x + threadIdx.x;
    if (e < NPAIR) rank[e] = atomicAdd(&cnt[oix[e]], 1);
    if (e < (N_VOX * CIN) / 4) {
        const int e4 = e * 4;
        const float4 v = *(const float4*)(feats + e4);
        ushort4 b;
        b.x = f32_to_bf16(v.x);
        b.y = f32_to_bf16(v.y);
        b.z = f32_to_bf16(v.z);
        b.w = f32_to_bf16(v.w);
        *(ushort4*)(fb + e4) = b;
    }
    if (e < K_OFF * CIN * COUT) {
        const int k = e / (CIN * COUT);
        const int r = e % (CIN * COUT);
        Wt[k * CIN * COUT + (r % COUT) * CIN + (r / COUT)] = f32_to_bf16(W[e]);
    }
}

// ---------- per-block alloc: LDS scan + one global allocator atomic ----------
__global__ __launch_bounds__(256) void alloc_kernel(
    const int* __restrict__ cnt, int* __restrict__ total, int* __restrict__ seg)
{
    __shared__ int part[256];
    __shared__ int bbase;
    const int t = threadIdx.x;
    const int v = blockIdx.x * 256 + t;
    const int c = (v < N_VOX) ? cnt[v] : 0;
    part[t] = c;
    __syncthreads();
    for (int o = 1; o < 256; o <<= 1) {
        int x = (t >= o) ? part[t - o] : 0;
        __syncthreads();
        part[t] += x;
        __syncthreads();
    }
    if (t == 255) bbase = atomicAdd(total, part[255]);
    __syncthreads();
    if (v < N_VOX) seg[v] = bbase + (part[t] - c);
}

// ---------- phase A: gather-GEMM, 2-stage pipelined, sorted-slot stores ----------
// 125 waves per k, 30 contiguous tiles each. Wave-private LDS slab, no
// __syncthreads, zero atomics. Next tile's idx/A-frags/slot prefetched during
// current tile's MFMA + LDS roundtrip + store (hides the idx->gather chain).
__global__ __launch_bounds__(256) void conv_scatter_kernel(
    const unsigned short* __restrict__ fb, const unsigned short* __restrict__ Wt,
    const int* __restrict__ in_idx, const int* __restrict__ out_idx,
    const int* __restrict__ rank, const int* __restrict__ seg,
    unsigned short* __restrict__ contrib)
{
    __shared__ alignas(16) unsigned short lds[4][16 * 72];
    const int k = blockIdx.y;
    const int lane = threadIdx.x & 63;
    const int wid = threadIdx.x >> 6;
    const int w = blockIdx.x * 4 + wid;
    if (w >= 125) return;
    const int col = lane & 15;
    const int quad = lane >> 4;
    unsigned short* L = lds[wid];

    bf16x8 Bf[4][2];
    const short* Wk = (const short*)(Wt + k * CIN * COUT);
#pragma unroll
    for (int t = 0; t < 4; ++t) {
        const short* p = Wk + (t * 16 + col) * CIN + quad * 8;
        Bf[t][0] = *(const bf16x8*)(p);
        Bf[t][1] = *(const bf16x8*)(p + 32);
    }

    int m0 = k * M_PAIR + (w * 30) * 16;
    // prologue: loads for tile 0
    int slot = 0;
    if (lane < 16) slot = seg[out_idx[m0 + lane]] + rank[m0 + lane];
    {
        const int rin = in_idx[m0 + col];
        const short* fp = (const short*)fb + (size_t)rin * CIN + quad * 8;
        bf16x8 A0 = *(const bf16x8*)(fp);
        bf16x8 A1 = *(const bf16x8*)(fp + 32);

        for (int it = 0; it < 30; ++it) {
            // ---- prefetch next tile (overlaps MFMA/LDS/store below) ----
            bf16x8 nA0 = A0, nA1 = A1;
            int nslot = slot;
            if (it + 1 < 30) {
                const int m1 = m0 + 16;
                if (lane < 16)
                    nslot = seg[out_idx[m1 + lane]] + rank[m1 + lane];
                const int rn = in_idx[m1 + col];
                const short* fn = (const short*)fb + (size_t)rn * CIN + quad * 8;
                nA0 = *(const bf16x8*)(fn);
                nA1 = *(const bf16x8*)(fn + 32);
            }

            f32x4 acc[4];
#pragma unroll
            for (int t = 0; t < 4; ++t) {
                f32x4 z = {0.f, 0.f, 0.f, 0.f};
                acc[t] = __builtin_amdgcn_mfma_f32_16x16x32_bf16(A0, Bf[t][0], z, 0, 0, 0);
                acc[t] = __builtin_amdgcn_mfma_f32_16x16x32_bf16(A1, Bf[t][1], acc[t], 0, 0, 0);
            }
            // C/D layout (cout = t*16+col, row = quad*4+r) -> LDS [row][72]
#pragma unroll
            for (int r = 0; r < 4; ++r) {
                const int row = quad * 4 + r;
#pragma unroll
                for (int t = 0; t < 4; ++t)
                    L[row * 72 + t * 16 + col] = f32_to_bf16(acc[t][r]);
            }
            // full-line 128B row stores to sorted slots
#pragma unroll
            for (int itr = 0; itr < 2; ++itr) {
                const int row = itr * 8 + (lane >> 3);
                const int chunk = lane & 7;
                const int pos = __shfl(slot, row, 64);
                const u16x8 v = *(const u16x8*)(L + row * 72 + chunk * 8);
                *(u16x8*)(contrib + (size_t)pos * 64 + chunk * 8) = v;
            }
            A0 = nA0;
            A1 = nA1;
            slot = nslot;
            m0 += 16;
        }
    }
}

// ---------- phase B: wide streaming segmented sum + fused BN + ReLU ----------
// 8 rows (1KB) per wave-load: lane = (row_in_group rg = lane>>3, chan-group
// cg = lane&7). Per-lane u16x8 accumulate, then 3x shfl_xor row reduction;
// lanes rg==0 apply BN and store float4 x2.
__global__ __launch_bounds__(256) void gather_bn_kernel(
    const unsigned short* __restrict__ contrib, const int* __restrict__ seg,
    const int* __restrict__ cnt,
    const float* __restrict__ gamma, const float* __restrict__ beta,
    const float* __restrict__ mean, const float* __restrict__ var,
    float* __restrict__ out)
{
    const int v = blockIdx.x * 4 + (threadIdx.x >> 6);   // one wave per voxel
    if (v >= N_VOX) return;
    const int lane = threadIdx.x & 63;
    const int rg = lane >> 3;          // row within 8-row group
    const int cg = lane & 7;           // channel group (8 ch)
    const int s = seg[v];
    const int n = cnt[v];

    float acc[8] = {0.f, 0.f, 0.f, 0.f, 0.f, 0.f, 0.f, 0.f};
    const unsigned short* base = contrib + (size_t)s * 64 + cg * 8;
    const int ngroups = (n + 7) >> 3;
    for (int g = 0; g < ngroups; ++g) {
        const int row = g * 8 + rg;
        if (row < n) {
            const u16x8 u = *(const u16x8*)(base + (size_t)row * 64);
#pragma unroll
            for (int i = 0; i < 8; ++i)
                acc[i] += bf16_to_f32((unsigned short)u[i]);
        }
    }
    // sum across the 8 row-lanes sharing this channel group
#pragma unroll
    for (int off = 8; off < 64; off <<= 1) {
#pragma unroll
        for (int i = 0; i < 8; ++i)
            acc[i] += __shfl_xor(acc[i], off, 64);
    }
    if (rg == 0) {
        const int ch = cg * 8;
        float4 r0, r1;
#pragma unroll
        for (int i = 0; i < 8; ++i) {
            const float inv = rsqrtf(var[ch + i] + BN_EPS);
            float y = (acc[i] - mean[ch + i]) * (inv * gamma[ch + i]) + beta[ch + i];
            y = fmaxf(y, 0.f);
            if (i < 4) ((float*)&r0)[i] = y;
            else       ((float*)&r1)[i - 4] = y;
        }
        *(float4*)(out + (size_t)v * 64 + ch) = r0;
        *(float4*)(out + (size_t)v * 64 + ch + 4) = r1;
    }
}

// ---------- fallback (atomic path, used if ws too small) ----------
__global__ __launch_bounds__(256) void prep_small_kernel(
    const float* __restrict__ feats, unsigned short* __restrict__ fb,
    float* __restrict__ out, const float* __restrict__ W,
    unsigned short* __restrict__ Wt)
{
    const int e = blockIdx.x * blockDim.x + threadIdx.x;
    if (e < (N_VOX * CIN) / 4) {
        const int e4 = e * 4;
        const float4 v = *(const float4*)(feats + e4);
        ushort4 b;
        b.x = f32_to_bf16(v.x);
        b.y = f32_to_bf16(v.y);
        b.z = f32_to_bf16(v.z);
        b.w = f32_to_bf16(v.w);
        *(ushort4*)(fb + e4) = b;
        *(float4*)(out + e4) = make_float4(0.f, 0.f, 0.f, 0.f);
    }
    if (e < K_OFF * CIN * COUT) {
        const int k = e / (CIN * COUT);
        const int r = e % (CIN * COUT);
        Wt[k * CIN * COUT + (r % COUT) * CIN + (r / COUT)] = f32_to_bf16(W[e]);
    }
}

__global__ __launch_bounds__(256) void conv_atomic_kernel(
    const unsigned short* __restrict__ fb, const unsigned short* __restrict__ Wt,
    const int* __restrict__ in_idx, const int* __restrict__ out_idx,
    float* __restrict__ out)
{
    const int k = blockIdx.y;
    const int lane = threadIdx.x & 63;
    const int wave = blockIdx.x * 4 + (threadIdx.x >> 6);
    const int col = lane & 15;
    const int quad = lane >> 4;
    bf16x8 Bf[4][2];
    const short* Wk = (const short*)(Wt + k * CIN * COUT);
#pragma unroll
    for (int t = 0; t < 4; ++t) {
        const short* p = Wk + (t * 16 + col) * CIN + quad * 8;
        Bf[t][0] = *(const bf16x8*)(p);
        Bf[t][1] = *(const bf16x8*)(p + 32);
    }
    const int base = k * M_PAIR;
    for (int tile = wave; tile < M_PAIR / 16; tile += 128) {
        const int m0 = base + tile * 16;
        const int rin = in_idx[m0 + col];
        const short* fp = (const short*)fb + (size_t)rin * CIN + quad * 8;
        const bf16x8 A0 = *(const bf16x8*)(fp);
        const bf16x8 A1 = *(const bf16x8*)(fp + 32);
        f32x4 acc[4];
#pragma unroll
        for (int t = 0; t < 4; ++t) {
            f32x4 z = {0.f, 0.f, 0.f, 0.f};
            acc[t] = __builtin_amdgcn_mfma_f32_16x16x32_bf16(A0, Bf[t][0], z, 0, 0, 0);
            acc[t] = __builtin_amdgcn_mfma_f32_16x16x32_bf16(A1, Bf[t][1], acc[t], 0, 0, 0);
        }
        int vo[4];
#pragma unroll
        for (int r = 0; r < 4; ++r) vo[r] = out_idx[m0 + quad * 4 + r];
#pragma unroll
        for (int r = 0; r < 4; ++r) {
            float* op = out + (size_t)vo[r] * COUT + col;
#pragma unroll
            for (int t = 0; t < 4; ++t) atomicAdd(op + t * 16, acc[t][r]);
        }
    }
}

__global__ __launch_bounds__(256) void bn_relu_kernel(
    float* __restrict__ out,
    const float* __restrict__ gamma, const float* __restrict__ beta,
    const float* __restrict__ mean, const float* __restrict__ var)
{
    const int e = blockIdx.x * blockDim.x + threadIdx.x;
    if (e >= N_VOX * COUT) return;
    const int c = e & (COUT - 1);
    const float inv = rsqrtf(var[c] + BN_EPS);
    const float y = (out[e] - mean[c]) * (inv * gamma[c]) + beta[c];
    out[e] = fmaxf(y, 0.f);
}

// ---------- host ----------
extern "C" void kernel_launch(void* const* d_in, const int* in_sizes, int n_in,
                              void* d_out, int out_size, void* d_ws, size_t ws_size,
                              hipStream_t stream) {
    const float* feats = (const float*)d_in[0];
    const float* W     = (const float*)d_in[1];
    const float* gamma = (const float*)d_in[2];
    const float* beta  = (const float*)d_in[3];
    const float* rmean = (const float*)d_in[4];
    const float* rvar  = (const float*)d_in[5];
    const int* in_idx  = (const int*)d_in[6];
    const int* out_idx = (const int*)d_in[7];
    float* out = (float*)d_out;

    char* ws = (char*)d_ws;
    size_t off = 0;
    auto alloc = [&](size_t bytes) {
        size_t p = off;
        off = (off + bytes + 255) & ~(size_t)255;
        return p;
    };
    const size_t o_fb   = alloc((size_t)N_VOX * CIN * 2);
    const size_t o_wt   = alloc((size_t)K_OFF * CIN * COUT * 2);
    const size_t o_cnt  = alloc((size_t)N_VOX * 4 + 4);  // cnt + adjacent total
    const size_t o_seg  = alloc((size_t)N_VOX * 4);
    const size_t o_rank = alloc((size_t)NPAIR * 4);
    const size_t o_ctr  = alloc((size_t)NPAIR * COUT * 2);
    const bool big = (ws_size >= off);       // constant across calls -> graph-safe

    unsigned short* fb  = (unsigned short*)(ws + o_fb);
    unsigned short* Wt  = (unsigned short*)(ws + o_wt);
    int* cnt            = (int*)(ws + o_cnt);
    int* total          = cnt + N_VOX;       // adjacent -> one memset covers both
    int* seg            = (int*)(ws + o_seg);
    int* rank           = (int*)(ws + o_rank);
    unsigned short* ctr = (unsigned short*)(ws + o_ctr);

    if (big) {
        hipMemsetAsync(cnt, 0, (size_t)N_VOX * 4 + 4, stream);
        prep_rank_kernel<<<(NPAIR + 255) / 256, 256, 0, stream>>>(
            out_idx, cnt, rank, feats, fb, W, Wt);
        alloc_kernel<<<(N_VOX + 255) / 256, 256, 0, stream>>>(cnt, total, seg);
        conv_scatter_kernel<<<dim3(32, K_OFF), 256, 0, stream>>>(
            fb, Wt, in_idx, out_idx, rank, seg, ctr);
        gather_bn_kernel<<<(N_VOX + 3) / 4, 256, 0, stream>>>(ctr, seg, cnt,
                                                              gamma, beta, rmean, rvar, out);
    } else {
        const int ptot = (N_VOX * CIN) / 4;
        prep_small_kernel<<<(ptot + 255) / 256, 256, 0, stream>>>(feats, fb, out, W, Wt);
        conv_atomic_kernel<<<dim3(32, K_OFF), 256, 0, stream>>>(fb, Wt, in_idx, out_idx, out);
        const int total_e = N_VOX * COUT;
        bn_relu_kernel<<<(total_e + 255) / 256, 256, 0, stream>>>(out, gamma, beta, rmean, rvar);
    }
}

// Round 13
// 290.138 us; speedup vs baseline: 2.3380x; 1.0462x over previous
//
#include <hip/hip_runtime.h>

#define N_VOX 100000
#define K_OFF 27
#define M_PAIR 60000
#define NPAIR (K_OFF * M_PAIR)
#define CIN 64
#define COUT 64
#define BN_EPS 1e-5f

typedef __attribute__((ext_vector_type(8))) short bf16x8;
typedef __attribute__((ext_vector_type(8))) unsigned short u16x8;
typedef __attribute__((ext_vector_type(4))) float f32x4;

__device__ __forceinline__ unsigned short f32_to_bf16(float f) {
    unsigned int u = __float_as_uint(f);
    u += 0x7FFFu + ((u >> 16) & 1u);
    return (unsigned short)(u >> 16);
}
__device__ __forceinline__ float bf16_to_f32(unsigned short b) {
    return __uint_as_float(((unsigned int)b) << 16);
}

// ---------- fused prep: hist atomic (rank = return value) + feats->bf16 + W^T ----------
__global__ __launch_bounds__(256) void prep_rank_kernel(
    const int* __restrict__ oix, int* __restrict__ cnt, int* __restrict__ rank,
    const float* __restrict__ feats, unsigned short* __restrict__ fb,
    const float* __restrict__ W, unsigned short* __restrict__ Wt)
{
    const int e = blockIdx.x * blockDim.x + threadIdx.x;
    if (e < NPAIR) rank[e] = atomicAdd(&cnt[oix[e]], 1);
    if (e < (N_VOX * CIN) / 4) {
        const int e4 = e * 4;
        const float4 v = *(const float4*)(feats + e4);
        ushort4 b;
        b.x = f32_to_bf16(v.x);
        b.y = f32_to_bf16(v.y);
        b.z = f32_to_bf16(v.z);
        b.w = f32_to_bf16(v.w);
        *(ushort4*)(fb + e4) = b;
    }
    if (e < K_OFF * CIN * COUT) {
        const int k = e / (CIN * COUT);
        const int r = e % (CIN * COUT);
        Wt[k * CIN * COUT + (r % COUT) * CIN + (r / COUT)] = f32_to_bf16(W[e]);
    }
}

// ---------- per-block alloc: LDS scan + one global allocator atomic ----------
__global__ __launch_bounds__(256) void alloc_kernel(
    const int* __restrict__ cnt, int* __restrict__ total, int* __restrict__ seg)
{
    __shared__ int part[256];
    __shared__ int bbase;
    const int t = threadIdx.x;
    const int v = blockIdx.x * 256 + t;
    const int c = (v < N_VOX) ? cnt[v] : 0;
    part[t] = c;
    __syncthreads();
    for (int o = 1; o < 256; o <<= 1) {
        int x = (t >= o) ? part[t - o] : 0;
        __syncthreads();
        part[t] += x;
        __syncthreads();
    }
    if (t == 255) bbase = atomicAdd(total, part[255]);
    __syncthreads();
    if (v < N_VOX) seg[v] = bbase + (part[t] - c);
}

// ---------- phase A: gather-GEMM, pipelined, NT sorted-slot stores ----------
// 125 waves per k, 30 contiguous tiles each. Wave-private LDS slab, no
// __syncthreads, zero atomics. Contrib stores are NON-TEMPORAL: write-once
// data, keeping fb/seg/rank L2-resident (fixes the 102MB FETCH refetch).
__global__ __launch_bounds__(256) void conv_scatter_kernel(
    const unsigned short* __restrict__ fb, const unsigned short* __restrict__ Wt,
    const int* __restrict__ in_idx, const int* __restrict__ out_idx,
    const int* __restrict__ rank, const int* __restrict__ seg,
    unsigned short* __restrict__ contrib)
{
    __shared__ alignas(16) unsigned short lds[4][16 * 72];
    const int k = blockIdx.y;
    const int lane = threadIdx.x & 63;
    const int wid = threadIdx.x >> 6;
    const int w = blockIdx.x * 4 + wid;
    if (w >= 125) return;
    const int col = lane & 15;
    const int quad = lane >> 4;
    unsigned short* L = lds[wid];

    bf16x8 Bf[4][2];
    const short* Wk = (const short*)(Wt + k * CIN * COUT);
#pragma unroll
    for (int t = 0; t < 4; ++t) {
        const short* p = Wk + (t * 16 + col) * CIN + quad * 8;
        Bf[t][0] = *(const bf16x8*)(p);
        Bf[t][1] = *(const bf16x8*)(p + 32);
    }

    int m0 = k * M_PAIR + (w * 30) * 16;
    int slot = 0;
    if (lane < 16) slot = seg[out_idx[m0 + lane]] + rank[m0 + lane];
    {
        const int rin = in_idx[m0 + col];
        const short* fp = (const short*)fb + (size_t)rin * CIN + quad * 8;
        bf16x8 A0 = *(const bf16x8*)(fp);
        bf16x8 A1 = *(const bf16x8*)(fp + 32);

        for (int it = 0; it < 30; ++it) {
            // prefetch next tile (overlaps MFMA/LDS/store below)
            bf16x8 nA0 = A0, nA1 = A1;
            int nslot = slot;
            if (it + 1 < 30) {
                const int m1 = m0 + 16;
                if (lane < 16)
                    nslot = seg[out_idx[m1 + lane]] + rank[m1 + lane];
                const int rn = in_idx[m1 + col];
                const short* fn = (const short*)fb + (size_t)rn * CIN + quad * 8;
                nA0 = *(const bf16x8*)(fn);
                nA1 = *(const bf16x8*)(fn + 32);
            }

            f32x4 acc[4];
#pragma unroll
            for (int t = 0; t < 4; ++t) {
                f32x4 z = {0.f, 0.f, 0.f, 0.f};
                acc[t] = __builtin_amdgcn_mfma_f32_16x16x32_bf16(A0, Bf[t][0], z, 0, 0, 0);
                acc[t] = __builtin_amdgcn_mfma_f32_16x16x32_bf16(A1, Bf[t][1], acc[t], 0, 0, 0);
            }
            // C/D layout (cout = t*16+col, row = quad*4+r) -> LDS [row][72]
#pragma unroll
            for (int r = 0; r < 4; ++r) {
                const int row = quad * 4 + r;
#pragma unroll
                for (int t = 0; t < 4; ++t)
                    L[row * 72 + t * 16 + col] = f32_to_bf16(acc[t][r]);
            }
            // full-line 128B row NT stores to sorted slots
#pragma unroll
            for (int itr = 0; itr < 2; ++itr) {
                const int row = itr * 8 + (lane >> 3);
                const int chunk = lane & 7;
                const int pos = __shfl(slot, row, 64);
                const u16x8 v = *(const u16x8*)(L + row * 72 + chunk * 8);
                __builtin_nontemporal_store(
                    v, (u16x8*)(contrib + (size_t)pos * 64 + chunk * 8));
            }
            A0 = nA0;
            A1 = nA1;
            slot = nslot;
            m0 += 16;
        }
    }
}

// ---------- phase B: streaming segmented sum + fused BN + ReLU (round-9 form,
// NT contrib loads: read-once stream, keep seg/cnt/params resident) ----------
__global__ __launch_bounds__(256) void gather_bn_kernel(
    const unsigned short* __restrict__ contrib, const int* __restrict__ seg,
    const int* __restrict__ cnt,
    const float* __restrict__ gamma, const float* __restrict__ beta,
    const float* __restrict__ mean, const float* __restrict__ var,
    float* __restrict__ out)
{
    const int v = blockIdx.x * 4 + (threadIdx.x >> 6);   // one wave per voxel
    if (v >= N_VOX) return;
    const int lane = threadIdx.x & 63;
    const int half = lane >> 5;        // 0: even rows, 1: odd rows
    const int l = lane & 31;           // uint index (channels 2l, 2l+1)
    const int s = seg[v];
    const int n = cnt[v];

    const unsigned int* p = (const unsigned int*)(contrib + (size_t)s * 64) + l;
    float c0 = 0.f, c1 = 0.f, d0 = 0.f, d1 = 0.f;
    int j = half;
    for (; j + 2 < n; j += 4) {
        const unsigned int u0 = __builtin_nontemporal_load(p + (size_t)j * 32);
        const unsigned int u1 = __builtin_nontemporal_load(p + (size_t)(j + 2) * 32);
        c0 += bf16_to_f32((unsigned short)u0);
        c1 += bf16_to_f32((unsigned short)(u0 >> 16));
        d0 += bf16_to_f32((unsigned short)u1);
        d1 += bf16_to_f32((unsigned short)(u1 >> 16));
    }
    if (j < n) {
        const unsigned int u0 = __builtin_nontemporal_load(p + (size_t)j * 32);
        c0 += bf16_to_f32((unsigned short)u0);
        c1 += bf16_to_f32((unsigned short)(u0 >> 16));
    }
    c0 += d0;
    c1 += d1;
    c0 += __shfl_xor(c0, 32, 64);
    c1 += __shfl_xor(c1, 32, 64);
    if (half == 0) {
        const int ch = 2 * l;
        const float inv0 = rsqrtf(var[ch] + BN_EPS);
        const float inv1 = rsqrtf(var[ch + 1] + BN_EPS);
        const float y0 = (c0 - mean[ch]) * (inv0 * gamma[ch]) + beta[ch];
        const float y1 = (c1 - mean[ch + 1]) * (inv1 * gamma[ch + 1]) + beta[ch + 1];
        float2 r;
        r.x = fmaxf(y0, 0.f);
        r.y = fmaxf(y1, 0.f);
        *(float2*)(out + (size_t)v * 64 + ch) = r;
    }
}

// ---------- fallback (atomic path, used if ws too small) ----------
__global__ __launch_bounds__(256) void prep_small_kernel(
    const float* __restrict__ feats, unsigned short* __restrict__ fb,
    float* __restrict__ out, const float* __restrict__ W,
    unsigned short* __restrict__ Wt)
{
    const int e = blockIdx.x * blockDim.x + threadIdx.x;
    if (e < (N_VOX * CIN) / 4) {
        const int e4 = e * 4;
        const float4 v = *(const float4*)(feats + e4);
        ushort4 b;
        b.x = f32_to_bf16(v.x);
        b.y = f32_to_bf16(v.y);
        b.z = f32_to_bf16(v.z);
        b.w = f32_to_bf16(v.w);
        *(ushort4*)(fb + e4) = b;
        *(float4*)(out + e4) = make_float4(0.f, 0.f, 0.f, 0.f);
    }
    if (e < K_OFF * CIN * COUT) {
        const int k = e / (CIN * COUT);
        const int r = e % (CIN * COUT);
        Wt[k * CIN * COUT + (r % COUT) * CIN + (r / COUT)] = f32_to_bf16(W[e]);
    }
}

__global__ __launch_bounds__(256) void conv_atomic_kernel(
    const unsigned short* __restrict__ fb, const unsigned short* __restrict__ Wt,
    const int* __restrict__ in_idx, const int* __restrict__ out_idx,
    float* __restrict__ out)
{
    const int k = blockIdx.y;
    const int lane = threadIdx.x & 63;
    const int wave = blockIdx.x * 4 + (threadIdx.x >> 6);
    const int col = lane & 15;
    const int quad = lane >> 4;
    bf16x8 Bf[4][2];
    const short* Wk = (const short*)(Wt + k * CIN * COUT);
#pragma unroll
    for (int t = 0; t < 4; ++t) {
        const short* p = Wk + (t * 16 + col) * CIN + quad * 8;
        Bf[t][0] = *(const bf16x8*)(p);
        Bf[t][1] = *(const bf16x8*)(p + 32);
    }
    const int base = k * M_PAIR;
    for (int tile = wave; tile < M_PAIR / 16; tile += 128) {
        const int m0 = base + tile * 16;
        const int rin = in_idx[m0 + col];
        const short* fp = (const short*)fb + (size_t)rin * CIN + quad * 8;
        const bf16x8 A0 = *(const bf16x8*)(fp);
        const bf16x8 A1 = *(const bf16x8*)(fp + 32);
        f32x4 acc[4];
#pragma unroll
        for (int t = 0; t < 4; ++t) {
            f32x4 z = {0.f, 0.f, 0.f, 0.f};
            acc[t] = __builtin_amdgcn_mfma_f32_16x16x32_bf16(A0, Bf[t][0], z, 0, 0, 0);
            acc[t] = __builtin_amdgcn_mfma_f32_16x16x32_bf16(A1, Bf[t][1], acc[t], 0, 0, 0);
        }
        int vo[4];
#pragma unroll
        for (int r = 0; r < 4; ++r) vo[r] = out_idx[m0 + quad * 4 + r];
#pragma unroll
        for (int r = 0; r < 4; ++r) {
            float* op = out + (size_t)vo[r] * COUT + col;
#pragma unroll
            for (int t = 0; t < 4; ++t) atomicAdd(op + t * 16, acc[t][r]);
        }
    }
}

__global__ __launch_bounds__(256) void bn_relu_kernel(
    float* __restrict__ out,
    const float* __restrict__ gamma, const float* __restrict__ beta,
    const float* __restrict__ mean, const float* __restrict__ var)
{
    const int e = blockIdx.x * blockDim.x + threadIdx.x;
    if (e >= N_VOX * COUT) return;
    const int c = e & (COUT - 1);
    const float inv = rsqrtf(var[c] + BN_EPS);
    const float y = (out[e] - mean[c]) * (inv * gamma[c]) + beta[c];
    out[e] = fmaxf(y, 0.f);
}

// ---------- host ----------
extern "C" void kernel_launch(void* const* d_in, const int* in_sizes, int n_in,
                              void* d_out, int out_size, void* d_ws, size_t ws_size,
                              hipStream_t stream) {
    const float* feats = (const float*)d_in[0];
    const float* W     = (const float*)d_in[1];
    const float* gamma = (const float*)d_in[2];
    const float* beta  = (const float*)d_in[3];
    const float* rmean = (const float*)d_in[4];
    const float* rvar  = (const float*)d_in[5];
    const int* in_idx  = (const int*)d_in[6];
    const int* out_idx = (const int*)d_in[7];
    float* out = (float*)d_out;

    char* ws = (char*)d_ws;
    size_t off = 0;
    auto alloc = [&](size_t bytes) {
        size_t p = off;
        off = (off + bytes + 255) & ~(size_t)255;
        return p;
    };
    const size_t o_fb   = alloc((size_t)N_VOX * CIN * 2);
    const size_t o_wt   = alloc((size_t)K_OFF * CIN * COUT * 2);
    const size_t o_cnt  = alloc((size_t)N_VOX * 4 + 4);  // cnt + adjacent total
    const size_t o_seg  = alloc((size_t)N_VOX * 4);
    const size_t o_rank = alloc((size_t)NPAIR * 4);
    const size_t o_ctr  = alloc((size_t)NPAIR * COUT * 2);
    const bool big = (ws_size >= off);       // constant across calls -> graph-safe

    unsigned short* fb  = (unsigned short*)(ws + o_fb);
    unsigned short* Wt  = (unsigned short*)(ws + o_wt);
    int* cnt            = (int*)(ws + o_cnt);
    int* total          = cnt + N_VOX;       // adjacent -> one memset covers both
    int* seg            = (int*)(ws + o_seg);
    int* rank           = (int*)(ws + o_rank);
    unsigned short* ctr = (unsigned short*)(ws + o_ctr);

    if (big) {
        hipMemsetAsync(cnt, 0, (size_t)N_VOX * 4 + 4, stream);
        prep_rank_kernel<<<(NPAIR + 255) / 256, 256, 0, stream>>>(
            out_idx, cnt, rank, feats, fb, W, Wt);
        alloc_kernel<<<(N_VOX + 255) / 256, 256, 0, stream>>>(cnt, total, seg);
        conv_scatter_kernel<<<dim3(32, K_OFF), 256, 0, stream>>>(
            fb, Wt, in_idx, out_idx, rank, seg, ctr);
        gather_bn_kernel<<<(N_VOX + 3) / 4, 256, 0, stream>>>(ctr, seg, cnt,
                                                              gamma, beta, rmean, rvar, out);
    } else {
        const int ptot = (N_VOX * CIN) / 4;
        prep_small_kernel<<<(ptot + 255) / 256, 256, 0, stream>>>(feats, fb, out, W, Wt);
        conv_atomic_kernel<<<dim3(32, K_OFF), 256, 0, stream>>>(fb, Wt, in_idx, out_idx, out);
        const int total_e = N_VOX * COUT;
        bn_relu_kernel<<<(total_e + 255) / 256, 256, 0, stream>>>(out, gamma, beta, rmean, rvar);
    }
}

// Round 14
// 283.238 us; speedup vs baseline: 2.3949x; 1.0244x over previous
//
#include <hip/hip_runtime.h>

#define N_VOX 100000
#define K_OFF 27
#define M_PAIR 60000
#define NPAIR (K_OFF * M_PAIR)
#define CIN 64
#define COUT 64
#define BN_EPS 1e-5f
#define CNT_STRIDE 16   // one voxel counter per 64B line: kills atomic line contention

typedef __attribute__((ext_vector_type(8))) short bf16x8;
typedef __attribute__((ext_vector_type(8))) unsigned short u16x8;
typedef __attribute__((ext_vector_type(4))) float f32x4;

__device__ __forceinline__ unsigned short f32_to_bf16(float f) {
    unsigned int u = __float_as_uint(f);
    u += 0x7FFFu + ((u >> 16) & 1u);
    return (unsigned short)(u >> 16);
}
__device__ __forceinline__ float bf16_to_f32(unsigned short b) {
    return __uint_as_float(((unsigned int)b) << 16);
}

// ---------- fused prep: hist atomic (rank = return value) + feats->bf16 + W^T ----------
// cnt is strided 64B/voxel: 1.62M atomics spread 16.2/line instead of 260/line.
__global__ __launch_bounds__(256) void prep_rank_kernel(
    const int* __restrict__ oix, int* __restrict__ cnt, int* __restrict__ rank,
    const float* __restrict__ feats, unsigned short* __restrict__ fb,
    const float* __restrict__ W, unsigned short* __restrict__ Wt)
{
    const int e = blockIdx.x * blockDim.x + threadIdx.x;
    if (e < NPAIR) rank[e] = atomicAdd(&cnt[oix[e] * CNT_STRIDE], 1);
    if (e < (N_VOX * CIN) / 4) {
        const int e4 = e * 4;
        const float4 v = *(const float4*)(feats + e4);
        ushort4 b;
        b.x = f32_to_bf16(v.x);
        b.y = f32_to_bf16(v.y);
        b.z = f32_to_bf16(v.z);
        b.w = f32_to_bf16(v.w);
        *(ushort4*)(fb + e4) = b;
    }
    if (e < K_OFF * CIN * COUT) {
        const int k = e / (CIN * COUT);
        const int r = e % (CIN * COUT);
        Wt[k * CIN * COUT + (r % COUT) * CIN + (r / COUT)] = f32_to_bf16(W[e]);
    }
}

// ---------- per-block alloc: LDS scan + one global allocator atomic ----------
__global__ __launch_bounds__(256) void alloc_kernel(
    const int* __restrict__ cnt, int* __restrict__ total, int* __restrict__ seg)
{
    __shared__ int part[256];
    __shared__ int bbase;
    const int t = threadIdx.x;
    const int v = blockIdx.x * 256 + t;
    const int c = (v < N_VOX) ? cnt[v * CNT_STRIDE] : 0;
    part[t] = c;
    __syncthreads();
    for (int o = 1; o < 256; o <<= 1) {
        int x = (t >= o) ? part[t - o] : 0;
        __syncthreads();
        part[t] += x;
        __syncthreads();
    }
    if (t == 255) bbase = atomicAdd(total, part[255]);
    __syncthreads();
    if (v < N_VOX) seg[v] = bbase + (part[t] - c);
}

// ---------- phase A: gather-GEMM, pipelined, NT sorted-slot stores ----------
__global__ __launch_bounds__(256) void conv_scatter_kernel(
    const unsigned short* __restrict__ fb, const unsigned short* __restrict__ Wt,
    const int* __restrict__ in_idx, const int* __restrict__ out_idx,
    const int* __restrict__ rank, const int* __restrict__ seg,
    unsigned short* __restrict__ contrib)
{
    __shared__ alignas(16) unsigned short lds[4][16 * 72];
    const int k = blockIdx.y;
    const int lane = threadIdx.x & 63;
    const int wid = threadIdx.x >> 6;
    const int w = blockIdx.x * 4 + wid;
    if (w >= 125) return;
    const int col = lane & 15;
    const int quad = lane >> 4;
    unsigned short* L = lds[wid];

    bf16x8 Bf[4][2];
    const short* Wk = (const short*)(Wt + k * CIN * COUT);
#pragma unroll
    for (int t = 0; t < 4; ++t) {
        const short* p = Wk + (t * 16 + col) * CIN + quad * 8;
        Bf[t][0] = *(const bf16x8*)(p);
        Bf[t][1] = *(const bf16x8*)(p + 32);
    }

    int m0 = k * M_PAIR + (w * 30) * 16;
    int slot = 0;
    if (lane < 16) slot = seg[out_idx[m0 + lane]] + rank[m0 + lane];
    {
        const int rin = in_idx[m0 + col];
        const short* fp = (const short*)fb + (size_t)rin * CIN + quad * 8;
        bf16x8 A0 = *(const bf16x8*)(fp);
        bf16x8 A1 = *(const bf16x8*)(fp + 32);

        for (int it = 0; it < 30; ++it) {
            bf16x8 nA0 = A0, nA1 = A1;
            int nslot = slot;
            if (it + 1 < 30) {
                const int m1 = m0 + 16;
                if (lane < 16)
                    nslot = seg[out_idx[m1 + lane]] + rank[m1 + lane];
                const int rn = in_idx[m1 + col];
                const short* fn = (const short*)fb + (size_t)rn * CIN + quad * 8;
                nA0 = *(const bf16x8*)(fn);
                nA1 = *(const bf16x8*)(fn + 32);
            }

            f32x4 acc[4];
#pragma unroll
            for (int t = 0; t < 4; ++t) {
                f32x4 z = {0.f, 0.f, 0.f, 0.f};
                acc[t] = __builtin_amdgcn_mfma_f32_16x16x32_bf16(A0, Bf[t][0], z, 0, 0, 0);
                acc[t] = __builtin_amdgcn_mfma_f32_16x16x32_bf16(A1, Bf[t][1], acc[t], 0, 0, 0);
            }
#pragma unroll
            for (int r = 0; r < 4; ++r) {
                const int row = quad * 4 + r;
#pragma unroll
                for (int t = 0; t < 4; ++t)
                    L[row * 72 + t * 16 + col] = f32_to_bf16(acc[t][r]);
            }
#pragma unroll
            for (int itr = 0; itr < 2; ++itr) {
                const int row = itr * 8 + (lane >> 3);
                const int chunk = lane & 7;
                const int pos = __shfl(slot, row, 64);
                const u16x8 v = *(const u16x8*)(L + row * 72 + chunk * 8);
                __builtin_nontemporal_store(
                    v, (u16x8*)(contrib + (size_t)pos * 64 + chunk * 8));
            }
            A0 = nA0;
            A1 = nA1;
            slot = nslot;
            m0 += 16;
        }
    }
}

// ---------- phase B: streaming segmented sum, 4-way MLP, fused BN + ReLU ----------
__global__ __launch_bounds__(256) void gather_bn_kernel(
    const unsigned short* __restrict__ contrib, const int* __restrict__ seg,
    const int* __restrict__ cnt,
    const float* __restrict__ gamma, const float* __restrict__ beta,
    const float* __restrict__ mean, const float* __restrict__ var,
    float* __restrict__ out)
{
    const int v = blockIdx.x * 4 + (threadIdx.x >> 6);   // one wave per voxel
    if (v >= N_VOX) return;
    const int lane = threadIdx.x & 63;
    const int half = lane >> 5;        // 0: even rows, 1: odd rows
    const int l = lane & 31;           // uint index (channels 2l, 2l+1)
    const int s = seg[v];
    const int n = cnt[v * CNT_STRIDE];

    const unsigned int* p = (const unsigned int*)(contrib + (size_t)s * 64) + l;
    float a0 = 0.f, a1 = 0.f, b0 = 0.f, b1 = 0.f;
    float c0 = 0.f, c1 = 0.f, d0 = 0.f, d1 = 0.f;
    int j = half;
    for (; j + 6 < n; j += 8) {        // 4 independent loads in flight
        const unsigned int u0 = __builtin_nontemporal_load(p + (size_t)j * 32);
        const unsigned int u1 = __builtin_nontemporal_load(p + (size_t)(j + 2) * 32);
        const unsigned int u2 = __builtin_nontemporal_load(p + (size_t)(j + 4) * 32);
        const unsigned int u3 = __builtin_nontemporal_load(p + (size_t)(j + 6) * 32);
        a0 += bf16_to_f32((unsigned short)u0);
        a1 += bf16_to_f32((unsigned short)(u0 >> 16));
        b0 += bf16_to_f32((unsigned short)u1);
        b1 += bf16_to_f32((unsigned short)(u1 >> 16));
        c0 += bf16_to_f32((unsigned short)u2);
        c1 += bf16_to_f32((unsigned short)(u2 >> 16));
        d0 += bf16_to_f32((unsigned short)u3);
        d1 += bf16_to_f32((unsigned short)(u3 >> 16));
    }
    for (; j < n; j += 2) {
        const unsigned int u0 = __builtin_nontemporal_load(p + (size_t)j * 32);
        a0 += bf16_to_f32((unsigned short)u0);
        a1 += bf16_to_f32((unsigned short)(u0 >> 16));
    }
    a0 += b0 + c0 + d0;
    a1 += b1 + c1 + d1;
    a0 += __shfl_xor(a0, 32, 64);
    a1 += __shfl_xor(a1, 32, 64);
    if (half == 0) {
        const int ch = 2 * l;
        const float inv0 = rsqrtf(var[ch] + BN_EPS);
        const float inv1 = rsqrtf(var[ch + 1] + BN_EPS);
        const float y0 = (a0 - mean[ch]) * (inv0 * gamma[ch]) + beta[ch];
        const float y1 = (a1 - mean[ch + 1]) * (inv1 * gamma[ch + 1]) + beta[ch + 1];
        float2 r;
        r.x = fmaxf(y0, 0.f);
        r.y = fmaxf(y1, 0.f);
        *(float2*)(out + (size_t)v * 64 + ch) = r;
    }
}

// ---------- fallback (atomic path, used if ws too small) ----------
__global__ __launch_bounds__(256) void prep_small_kernel(
    const float* __restrict__ feats, unsigned short* __restrict__ fb,
    float* __restrict__ out, const float* __restrict__ W,
    unsigned short* __restrict__ Wt)
{
    const int e = blockIdx.x * blockDim.x + threadIdx.x;
    if (e < (N_VOX * CIN) / 4) {
        const int e4 = e * 4;
        const float4 v = *(const float4*)(feats + e4);
        ushort4 b;
        b.x = f32_to_bf16(v.x);
        b.y = f32_to_bf16(v.y);
        b.z = f32_to_bf16(v.z);
        b.w = f32_to_bf16(v.w);
        *(ushort4*)(fb + e4) = b;
        *(float4*)(out + e4) = make_float4(0.f, 0.f, 0.f, 0.f);
    }
    if (e < K_OFF * CIN * COUT) {
        const int k = e / (CIN * COUT);
        const int r = e % (CIN * COUT);
        Wt[k * CIN * COUT + (r % COUT) * CIN + (r / COUT)] = f32_to_bf16(W[e]);
    }
}

__global__ __launch_bounds__(256) void conv_atomic_kernel(
    const unsigned short* __restrict__ fb, const unsigned short* __restrict__ Wt,
    const int* __restrict__ in_idx, const int* __restrict__ out_idx,
    float* __restrict__ out)
{
    const int k = blockIdx.y;
    const int lane = threadIdx.x & 63;
    const int wave = blockIdx.x * 4 + (threadIdx.x >> 6);
    const int col = lane & 15;
    const int quad = lane >> 4;
    bf16x8 Bf[4][2];
    const short* Wk = (const short*)(Wt + k * CIN * COUT);
#pragma unroll
    for (int t = 0; t < 4; ++t) {
        const short* p = Wk + (t * 16 + col) * CIN + quad * 8;
        Bf[t][0] = *(const bf16x8*)(p);
        Bf[t][1] = *(const bf16x8*)(p + 32);
    }
    const int base = k * M_PAIR;
    for (int tile = wave; tile < M_PAIR / 16; tile += 128) {
        const int m0 = base + tile * 16;
        const int rin = in_idx[m0 + col];
        const short* fp = (const short*)fb + (size_t)rin * CIN + quad * 8;
        const bf16x8 A0 = *(const bf16x8*)(fp);
        const bf16x8 A1 = *(const bf16x8*)(fp + 32);
        f32x4 acc[4];
#pragma unroll
        for (int t = 0; t < 4; ++t) {
            f32x4 z = {0.f, 0.f, 0.f, 0.f};
            acc[t] = __builtin_amdgcn_mfma_f32_16x16x32_bf16(A0, Bf[t][0], z, 0, 0, 0);
            acc[t] = __builtin_amdgcn_mfma_f32_16x16x32_bf16(A1, Bf[t][1], acc[t], 0, 0, 0);
        }
        int vo[4];
#pragma unroll
        for (int r = 0; r < 4; ++r) vo[r] = out_idx[m0 + quad * 4 + r];
#pragma unroll
        for (int r = 0; r < 4; ++r) {
            float* op = out + (size_t)vo[r] * COUT + col;
#pragma unroll
            for (int t = 0; t < 4; ++t) atomicAdd(op + t * 16, acc[t][r]);
        }
    }
}

__global__ __launch_bounds__(256) void bn_relu_kernel(
    float* __restrict__ out,
    const float* __restrict__ gamma, const float* __restrict__ beta,
    const float* __restrict__ mean, const float* __restrict__ var)
{
    const int e = blockIdx.x * blockDim.x + threadIdx.x;
    if (e >= N_VOX * COUT) return;
    const int c = e & (COUT - 1);
    const float inv = rsqrtf(var[c] + BN_EPS);
    const float y = (out[e] - mean[c]) * (inv * gamma[c]) + beta[c];
    out[e] = fmaxf(y, 0.f);
}

// ---------- host ----------
extern "C" void kernel_launch(void* const* d_in, const int* in_sizes, int n_in,
                              void* d_out, int out_size, void* d_ws, size_t ws_size,
                              hipStream_t stream) {
    const float* feats = (const float*)d_in[0];
    const float* W     = (const float*)d_in[1];
    const float* gamma = (const float*)d_in[2];
    const float* beta  = (const float*)d_in[3];
    const float* rmean = (const float*)d_in[4];
    const float* rvar  = (const float*)d_in[5];
    const int* in_idx  = (const int*)d_in[6];
    const int* out_idx = (const int*)d_in[7];
    float* out = (float*)d_out;

    char* ws = (char*)d_ws;
    size_t off = 0;
    auto alloc = [&](size_t bytes) {
        size_t p = off;
        off = (off + bytes + 255) & ~(size_t)255;
        return p;
    };
    const size_t o_fb   = alloc((size_t)N_VOX * CIN * 2);
    const size_t o_wt   = alloc((size_t)K_OFF * CIN * COUT * 2);
    const size_t o_cnt  = alloc((size_t)N_VOX * CNT_STRIDE * 4 + 4);  // strided cnt + total
    const size_t o_seg  = alloc((size_t)N_VOX * 4);
    const size_t o_rank = alloc((size_t)NPAIR * 4);
    const size_t o_ctr  = alloc((size_t)NPAIR * COUT * 2);
    const bool big = (ws_size >= off);       // constant across calls -> graph-safe

    unsigned short* fb  = (unsigned short*)(ws + o_fb);
    unsigned short* Wt  = (unsigned short*)(ws + o_wt);
    int* cnt            = (int*)(ws + o_cnt);
    int* total          = cnt + (size_t)N_VOX * CNT_STRIDE;  // adjacent
    int* seg            = (int*)(ws + o_seg);
    int* rank           = (int*)(ws + o_rank);
    unsigned short* ctr = (unsigned short*)(ws + o_ctr);

    if (big) {
        hipMemsetAsync(cnt, 0, (size_t)N_VOX * CNT_STRIDE * 4 + 4, stream);
        prep_rank_kernel<<<(NPAIR + 255) / 256, 256, 0, stream>>>(
            out_idx, cnt, rank, feats, fb, W, Wt);
        alloc_kernel<<<(N_VOX + 255) / 256, 256, 0, stream>>>(cnt, total, seg);
        conv_scatter_kernel<<<dim3(32, K_OFF), 256, 0, stream>>>(
            fb, Wt, in_idx, out_idx, rank, seg, ctr);
        gather_bn_kernel<<<(N_VOX + 3) / 4, 256, 0, stream>>>(ctr, seg, cnt,
                                                              gamma, beta, rmean, rvar, out);
    } else {
        const int ptot = (N_VOX * CIN) / 4;
        prep_small_kernel<<<(ptot + 255) / 256, 256, 0, stream>>>(feats, fb, out, W, Wt);
        conv_atomic_kernel<<<dim3(32, K_OFF), 256, 0, stream>>>(fb, Wt, in_idx, out_idx, out);
        const int total_e = N_VOX * COUT;
        bn_relu_kernel<<<(total_e + 255) / 256, 256, 0, stream>>>(out, gamma, beta, rmean, rvar);
    }
}